// Round 17
// baseline (196.542 us; speedup 1.0000x reference)
//
#include <hip/hip_runtime.h>
#include <hip/hip_bf16.h>
#include <math.h>

#define T_SEQ   2048
#define DM      1024
#define KF      32
#define BATCH   16
#define CPDIM   528
#define KPAD    544               // CPDIM padded to 17*32 for the final GEMM
#define YSTR    552               // Y/Qe LDS row stride (halves)
#define MROWS   (BATCH * T_SEQ)   // 32768
#define NCHUNK  32
#define TCHUNK  64

typedef __bf16 bf16x8 __attribute__((ext_vector_type(8)));
typedef float f32x4 __attribute__((ext_vector_type(4)));
typedef unsigned uint2v __attribute__((ext_vector_type(2)));

// split v into bf16 hi (RNE) + bf16 lo (trunc of residual), packed (hi<<16)|lo
__device__ __forceinline__ unsigned packsplit(float v) {
  unsigned u = __float_as_uint(v);
  unsigned h = (u + 0x7fffu + ((u >> 16) & 1u)) & 0xffff0000u;
  float rr = v - __uint_as_float(h);
  return h | (__float_as_uint(rr) >> 16);
}

// RNE f32 -> bf16 (as u16)
__device__ __forceinline__ unsigned short f2bf(float f) {
  unsigned u = __float_as_uint(f);
  return (unsigned short)((u + 0x7fffu + ((u >> 16) & 1u)) >> 16);
}
__device__ __forceinline__ float bf2f(unsigned short h) {
  return __uint_as_float((unsigned)h << 16);
}

// async global->LDS, 16 bytes per lane (dest = wave-uniform base + lane*16)
__device__ __forceinline__ void gload16(const void* g, void* l) {
  __builtin_amdgcn_global_load_lds(
      (const __attribute__((address_space(1))) unsigned*)g,
      (__attribute__((address_space(3))) unsigned*)l, 16, 0, 0);
}

// ---------------------------------------------------------------------------
// Kernel 1a: split-K fold partials. Grid (32 s-chunks, 16 i-tiles).
// ---------------------------------------------------------------------------
__global__ __launch_bounds__(256) void k_fold_part(const float* __restrict__ pre_w,
                                                   const float* __restrict__ qf,
                                                   const float* __restrict__ kfil,
                                                   float* __restrict__ Wp) {
  const int sc = blockIdx.x;   // 0..31
  const int it = blockIdx.y;   // 0..15
  const int s0 = sc * 64, i0 = it * 64;
  const int tid = threadIdx.x;
  __shared__ float fs[64][64];
  __shared__ float ps[64][64];
  for (int idx = tid; idx < 4096; idx += 256) {
    const int s = idx >> 6, c = idx & 63;
    fs[s][c] = (c < KF) ? qf[(s0 + s) * KF + c] : kfil[(s0 + s) * KF + c - KF];
    ps[s][c] = pre_w[(size_t)(s0 + s) * DM + i0 + c];
  }
  __syncthreads();
  const int i = tid & 63;
  const int kb = tid >> 6;
  float acc[16] = {};
  for (int s = 0; s < 64; ++s) {
    const float pv = ps[s][i];
    const float4 f0 = *reinterpret_cast<const float4*>(&fs[s][kb * 16 + 0]);
    const float4 f1 = *reinterpret_cast<const float4*>(&fs[s][kb * 16 + 4]);
    const float4 f2 = *reinterpret_cast<const float4*>(&fs[s][kb * 16 + 8]);
    const float4 f3 = *reinterpret_cast<const float4*>(&fs[s][kb * 16 + 12]);
    acc[0]  = fmaf(pv, f0.x, acc[0]);  acc[1]  = fmaf(pv, f0.y, acc[1]);
    acc[2]  = fmaf(pv, f0.z, acc[2]);  acc[3]  = fmaf(pv, f0.w, acc[3]);
    acc[4]  = fmaf(pv, f1.x, acc[4]);  acc[5]  = fmaf(pv, f1.y, acc[5]);
    acc[6]  = fmaf(pv, f1.z, acc[6]);  acc[7]  = fmaf(pv, f1.w, acc[7]);
    acc[8]  = fmaf(pv, f2.x, acc[8]);  acc[9]  = fmaf(pv, f2.y, acc[9]);
    acc[10] = fmaf(pv, f2.z, acc[10]); acc[11] = fmaf(pv, f2.w, acc[11]);
    acc[12] = fmaf(pv, f3.x, acc[12]); acc[13] = fmaf(pv, f3.y, acc[13]);
    acc[14] = fmaf(pv, f3.z, acc[14]); acc[15] = fmaf(pv, f3.w, acc[15]);
  }
#pragma unroll
  for (int j = 0; j < 16; ++j)
    Wp[((size_t)sc * 64 + kb * 16 + j) * DM + i0 + i] = acc[j];
}

// ---------------------------------------------------------------------------
// Kernel 1b: reduce partials -> Wt hi/lo; block 256 does the bias fold.
// ---------------------------------------------------------------------------
__global__ __launch_bounds__(256) void k_foldred_bias(const float* __restrict__ Wp,
                                                      const float* __restrict__ pre_b,
                                                      const float* __restrict__ qf,
                                                      const float* __restrict__ kfil,
                                                      unsigned short* __restrict__ Wt_hi,
                                                      unsigned short* __restrict__ Wt_lo,
                                                      float* __restrict__ bias64) {
  if (blockIdx.x == 256) {
    __shared__ float part[4][64];
    const int k = threadIdx.x & 63;
    const int q = threadIdx.x >> 6;
    float acc = 0.f;
    for (int s = q * 512; s < (q + 1) * 512; ++s) {
      const float fv = (k < KF) ? qf[s * KF + k] : kfil[s * KF + k - KF];
      acc = fmaf(pre_b[s], fv, acc);
    }
    part[q][k] = acc;
    __syncthreads();
    if (threadIdx.x < 64)
      bias64[threadIdx.x] = part[0][k] + part[1][k] + part[2][k] + part[3][k];
    return;
  }
  const int idx = blockIdx.x * 256 + threadIdx.x;  // k*1024+i
  float acc = 0.f;
#pragma unroll
  for (int sc = 0; sc < NCHUNK; ++sc)
    acc += Wp[(size_t)sc * 64 * DM + idx];
  const unsigned pk = packsplit(acc);
  Wt_hi[idx] = (unsigned short)(pk >> 16);
  Wt_lo[idx] = (unsigned short)(pk & 0xffffu);
}

// ---------------------------------------------------------------------------
// Kernel 2: Q0V = x @ Wt^T + bias64 (3-term split MFMA) FUSED with per-chunk
// sums of Z.  CONTIGUOUS-X version: K-supersteps of 256; each wave's 64
// lanes read ONE row's contiguous 1 KB via gload16 (per-lane swizzled source
// within the burst). Wt staged per-superstep (L2-resident). 8 pure-compute
// substeps between two barriers per superstep; K order 0..1023 ascending.
// LDS 136 KB -> 1 block/CU (bulk-BW-bound, latency hiding not critical).
// ---------------------------------------------------------------------------
__global__ __launch_bounds__(512) void k_q0v_cs(const float* __restrict__ x,
                                                const unsigned short* __restrict__ Wt_hi,
                                                const unsigned short* __restrict__ Wt_lo,
                                                const float* __restrict__ bias64,
                                                const float* __restrict__ decay,
                                                float* __restrict__ Q0V,
                                                float* __restrict__ S) {
  __shared__ float XsBig[64 * 256];              // 64 KB
  __shared__ unsigned short WhBig[8 * 64 * 32];  // 32 KB
  __shared__ unsigned short WlBig[8 * 64 * 32];  // 32 KB
  __shared__ float vs2[64 * 32];                 // 8 KB
  __shared__ float dec2[64];
  const int tid = threadIdx.x;
  const int m0 = blockIdx.x * 64;
  const int w = tid >> 6, l = tid & 63;
  const int g = l >> 4, r = l & 15;
  const int wr = w & 3, wh = w >> 2;             // row group / n half

  f32x4 acc[2] = {};

  auto compute = [&](int kk) {
    const int arow = wr * 16 + r;
    const int sx = (2 * g) ^ (arow & 7);
    const int sy = (2 * g + 1) ^ (arow & 7);
    const f32x4 pX = *reinterpret_cast<const f32x4*>(&XsBig[arow * 256 + kk * 32 + sx * 4]);
    const f32x4 pY = *reinterpret_cast<const f32x4*>(&XsBig[arow * 256 + kk * 32 + sy * 4]);
    unsigned pk[8];
#pragma unroll
    for (int e = 0; e < 4; ++e) { pk[e] = packsplit(pX[e]); pk[4 + e] = packsplit(pY[e]); }
    union { unsigned u[4]; bf16x8 v; } ah, al;
#pragma unroll
    for (int j = 0; j < 4; ++j) {
      ah.u[j] = (pk[2 * j] >> 16) | (pk[2 * j + 1] & 0xffff0000u);
      al.u[j] = (pk[2 * j] & 0xffffu) | (pk[2 * j + 1] << 16);
    }
    bf16x8 bh[2], bl[2];
#pragma unroll
    for (int nb = 0; nb < 2; ++nb) {
      const int brow = (wh * 2 + nb) * 16 + r;
      const int bs = g ^ ((brow >> 1) & 3);
      const int off = kk * 2048 + brow * 32 + bs * 8;
      bh[nb] = *reinterpret_cast<const bf16x8*>(&WhBig[off]);
      bl[nb] = *reinterpret_cast<const bf16x8*>(&WlBig[off]);
    }
#pragma unroll
    for (int nb = 0; nb < 2; ++nb) {
      acc[nb] = __builtin_amdgcn_mfma_f32_16x16x32_bf16(bh[nb], ah.v, acc[nb], 0, 0, 0);
      acc[nb] = __builtin_amdgcn_mfma_f32_16x16x32_bf16(bh[nb], al.v, acc[nb], 0, 0, 0);
      acc[nb] = __builtin_amdgcn_mfma_f32_16x16x32_bf16(bl[nb], ah.v, acc[nb], 0, 0, 0);
    }
  };

  if (tid < 64) dec2[tid] = decay[(m0 & 2047) + tid];

  for (int s = 0; s < 4; ++s) {
    __syncthreads();   // previous superstep's compute done reading LDS
    // ---- stage x: per wave, 64 lanes cover ONE row's contiguous 1 KB ----
#pragma unroll
    for (int q = 0; q < 8; ++q) {
      const int c = q * 512 + tid;              // 0..4095 chunks of 16 B
      const int row = c >> 6, l6 = c & 63;
      const int cq = (l6 & 56) | ((l6 & 7) ^ (row & 7));   // swizzled quad
      gload16(&x[(size_t)(m0 + row) * DM + s * 256 + cq * 4], &XsBig[c * 4]);
    }
    // ---- stage Wt hi/lo for all 8 substeps (L2-resident source) ----
#pragma unroll
    for (int q = 0; q < 4; ++q) {
      const int c = q * 512 + tid;              // 0..2047 chunks of 16 B
      const int kk = c >> 8, row = (c >> 2) & 63, sl = c & 3;
      const int colh = kk * 32 + (sl ^ ((row >> 1) & 3)) * 8;
      gload16(&Wt_hi[(size_t)row * DM + s * 256 + colh], &WhBig[c * 8]);
      gload16(&Wt_lo[(size_t)row * DM + s * 256 + colh], &WlBig[c * 8]);
    }
    __syncthreads();   // implicit vmcnt(0) drain -> tiles resident
#pragma unroll
    for (int kk = 0; kk < 8; ++kk)
      compute(kk);
  }

  // epilogue: write Q0V; stash V part (cols 32..63) in LDS for chunk sums
  const int trow = wr * 16 + r;
  const int row_o = m0 + trow;
#pragma unroll
  for (int nb = 0; nb < 2; ++nb) {
    const int n = wh * 2 + nb;
    const int col_o = n * 16 + g * 4;
    const float4 bb = *reinterpret_cast<const float4*>(&bias64[col_o]);
    float4 v;
    v.x = acc[nb][0] + bb.x; v.y = acc[nb][1] + bb.y;
    v.z = acc[nb][2] + bb.z; v.w = acc[nb][3] + bb.w;
    *reinterpret_cast<float4*>(&Q0V[(size_t)row_o * 64 + col_o]) = v;
    if (n >= 2)
      *reinterpret_cast<float4*>(&vs2[trow * 32 + (n - 2) * 16 + g * 4]) = v;
  }
  __syncthreads();

  const int b = m0 >> 11, ch = (m0 & 2047) >> 6;
#pragma unroll
  for (int pass = 0; pass < 2; ++pass) {
    const int c = tid + pass * 512;
    if (c < CPDIM) {
      int i = 0, rem = c;
      while (rem >= KF - i) { rem -= KF - i; ++i; }
      const int j = i + rem;
      const float sc = (i == j) ? 1.0f : 1.41421356237309515f;
      float h = 0.f;
#pragma unroll 4
      for (int t = 0; t < TCHUNK; ++t)
        h = fmaf(vs2[t * KF + i] * vs2[t * KF + j], dec2[t], h);
      S[(size_t)(b * NCHUNK + ch) * CPDIM + c] = h * sc;
    }
  }
}

// ---------------------------------------------------------------------------
// Kernel 3: exclusive scan of chunk sums (in place).
// ---------------------------------------------------------------------------
__global__ __launch_bounds__(576) void k_scanchunks(float* __restrict__ S) {
  const int b = blockIdx.x;
  const int c = threadIdx.x;
  if (c >= CPDIM) return;
  float v[NCHUNK];
#pragma unroll
  for (int ch = 0; ch < NCHUNK; ++ch)
    v[ch] = S[(size_t)(b * NCHUNK + ch) * CPDIM + c];
  float run = 0.f;
#pragma unroll
  for (int ch = 0; ch < NCHUNK; ++ch) {
    S[(size_t)(b * NCHUNK + ch) * CPDIM + c] = run;
    run += v[ch];
  }
}

// ---------------------------------------------------------------------------
// Kernel 4: prep — o_w -> bf16 [1024][544]; qp_w -> split hi/lo bf16 [544][32];
// qp_b -> padded f32 [544].
// ---------------------------------------------------------------------------
#define NB_OWB  (DM * KPAD / 256)           // 2176
#define NB_QPW  (KPAD * KF / 256)           // 68
__global__ __launch_bounds__(256) void k_prep(const float* __restrict__ ow,
                                              const float* __restrict__ qp_w,
                                              const float* __restrict__ qp_b,
                                              unsigned short* __restrict__ owb,
                                              unsigned short* __restrict__ qpw_hi,
                                              unsigned short* __restrict__ qpw_lo,
                                              float* __restrict__ qpb_pad) {
  const int bx = blockIdx.x;
  if (bx < NB_OWB) {
    const int idx = bx * 256 + threadIdx.x;
    const int n = idx / KPAD, k = idx - n * KPAD;
    owb[idx] = (k < CPDIM) ? f2bf(ow[(size_t)n * CPDIM + k]) : (unsigned short)0;
  } else if (bx < NB_OWB + NB_QPW) {
    const int idx = (bx - NB_OWB) * 256 + threadIdx.x;   // c*32+q
    const int c = idx >> 5;
    unsigned pk = 0;
    if (c < CPDIM) pk = packsplit(qp_w[idx]);
    qpw_hi[idx] = (unsigned short)(pk >> 16);
    qpw_lo[idx] = (unsigned short)(pk & 0xffffu);
  } else {
    for (int c = threadIdx.x; c < KPAD; c += 256)
      qpb_pad[c] = (c < CPDIM) ? qp_b[c] : 0.f;
  }
}

// ---------------------------------------------------------------------------
// Kernel 5: FUSED chunk pipeline, 16 waves, LDS = Ylds only (round-16 best).
// ---------------------------------------------------------------------------
__global__ __launch_bounds__(1024, 4) void k_out_fused(const float* __restrict__ Q0V,
                                                       const float* __restrict__ S,
                                                       const unsigned short* __restrict__ qpw_hi,
                                                       const unsigned short* __restrict__ qpw_lo,
                                                       const float* __restrict__ qpb_pad,
                                                       const float* __restrict__ decay,
                                                       const unsigned short* __restrict__ owb,
                                                       const float* __restrict__ ob,
                                                       float* __restrict__ out) {
  __shared__ unsigned short Ylds[64 * YSTR];   // 69 KB (Qe, then Y in place)
  const int tid = threadIdx.x;
  const int m0 = blockIdx.x * 64;
  const int b = m0 >> 11, ch = (m0 & 2047) >> 6;
  const int t0 = m0 & 2047;
  const int wv = tid >> 6, l = tid & 63;
  const int g = l >> 4, r = l & 15;

  // ---- phase 1a: Qe = qp_b + Q0 @ qp_w^T; A-frags straight from global ----
  {
    bf16x8 qah[4], qal[4];
#pragma unroll
    for (int m = 0; m < 4; ++m) {
      const int t = m * 16 + r;
      const f32x4 x0 = *reinterpret_cast<const f32x4*>(&Q0V[(size_t)(m0 + t) * 64 + g * 8]);
      const f32x4 x1 = *reinterpret_cast<const f32x4*>(&Q0V[(size_t)(m0 + t) * 64 + g * 8 + 4]);
      unsigned pk[8];
#pragma unroll
      for (int e = 0; e < 4; ++e) { pk[e] = packsplit(x0[e]); pk[4 + e] = packsplit(x1[e]); }
      union { unsigned u[4]; bf16x8 v; } hh, ll;
#pragma unroll
      for (int j = 0; j < 4; ++j) {
        hh.u[j] = (pk[2 * j] >> 16) | (pk[2 * j + 1] & 0xffff0000u);
        ll.u[j] = (pk[2 * j] & 0xffffu) | (pk[2 * j + 1] << 16);
      }
      qah[m] = hh.v; qal[m] = ll.v;
    }
    for (int nt = wv; nt < KPAD / 16; nt += 16) {
      const int crow = nt * 16 + r;
      const bf16x8 bh = *reinterpret_cast<const bf16x8*>(&qpw_hi[crow * KF + g * 8]);
      const bf16x8 bl = *reinterpret_cast<const bf16x8*>(&qpw_lo[crow * KF + g * 8]);
      const int cbase = nt * 16 + g * 4;
      const float4 qb4 = *reinterpret_cast<const float4*>(&qpb_pad[cbase]);
      f32x4 a[4];
#pragma unroll
      for (int m = 0; m < 4; ++m) { a[m][0] = qb4.x; a[m][1] = qb4.y; a[m][2] = qb4.z; a[m][3] = qb4.w; }
#pragma unroll
      for (int m = 0; m < 4; ++m) {
        a[m] = __builtin_amdgcn_mfma_f32_16x16x32_bf16(bh, qah[m], a[m], 0, 0, 0);
        a[m] = __builtin_amdgcn_mfma_f32_16x16x32_bf16(bh, qal[m], a[m], 0, 0, 0);
        a[m] = __builtin_amdgcn_mfma_f32_16x16x32_bf16(bl, qah[m], a[m], 0, 0, 0);
      }
#pragma unroll
      for (int m = 0; m < 4; ++m) {
        const int t = m * 16 + r;
        union { unsigned short s[4]; unsigned u[2]; } pk4;
#pragma unroll
        for (int j = 0; j < 4; ++j) pk4.s[j] = f2bf(a[m][j]);
        *reinterpret_cast<uint2v*>(&Ylds[t * YSTR + cbase]) = uint2v{pk4.u[0], pk4.u[1]};
      }
    }
  }
  __syncthreads();

  // ---- phase 1b: Y[t][c] = Qe[t][c] * H[t][c]; V from global Q0V tile ----
  if (tid < CPDIM) {
    const int c = tid;
    int i = 0, rem = c;
    while (rem >= KF - i) { rem -= KF - i; ++i; }
    const int j = i + rem;
    const float sc = (i == j) ? 1.0f : 1.41421356237309515f;
    const float* vrow = &Q0V[(size_t)m0 * 64 + 32];
    float h = S[(size_t)(b * NCHUNK + ch) * CPDIM + c];
#pragma unroll 8
    for (int t = 0; t < TCHUNK; ++t) {
      const float vi = vrow[t * 64 + i];
      const float vj = vrow[t * 64 + j];
      h = fmaf(vi * vj * sc, decay[t0 + t], h);
      const float qv = bf2f(Ylds[t * YSTR + c]);
      Ylds[t * YSTR + c] = f2bf(qv * h);
    }
  }
  __syncthreads();

  // ---- phase 2: out[m0..m0+63][:] = Y @ owb^T + ob; wave -> 64 cols ----
  f32x4 acc[4][4] = {};
  bf16x8 bfA[4], bfB[4];

  auto loadB = [&](bf16x8 (&dst)[4], int ks) {
    const int kh = ks * 32 + g * 8;
#pragma unroll
    for (int n = 0; n < 4; ++n)
      dst[n] = *reinterpret_cast<const bf16x8*>(&owb[(size_t)(wv * 64 + n * 16 + r) * KPAD + kh]);
  };
  auto step = [&](const bf16x8 (&bc)[4], int ks) {
    const int kh = ks * 32 + g * 8;
    bf16x8 af[4];
#pragma unroll
    for (int m = 0; m < 4; ++m)
      af[m] = *reinterpret_cast<const bf16x8*>(&Ylds[(m * 16 + r) * YSTR + kh]);
#pragma unroll
    for (int m = 0; m < 4; ++m)
#pragma unroll
      for (int n = 0; n < 4; ++n)
        acc[m][n] = __builtin_amdgcn_mfma_f32_16x16x32_bf16(bc[n], af[m], acc[m][n], 0, 0, 0);
  };

  loadB(bfA, 0);
#pragma unroll
  for (int ks = 0; ks < 16; ks += 2) {
    loadB(bfB, ks + 1);
    step(bfA, ks);
    loadB(bfA, ks + 2);   // ks+2 <= 16, valid
    step(bfB, ks + 1);
  }
  step(bfA, 16);

  // D row-idx(g*4+j) <-> owb side (out col), col-idx(r) <-> Y side (out row)
#pragma unroll
  for (int m = 0; m < 4; ++m) {
    const int row_o = m0 + m * 16 + r;
#pragma unroll
    for (int n = 0; n < 4; ++n) {
      const int col_o = wv * 64 + n * 16 + g * 4;
      const float4 bb = *reinterpret_cast<const float4*>(&ob[col_o]);
      float4 v;
      v.x = acc[m][n][0] + bb.x; v.y = acc[m][n][1] + bb.y;
      v.z = acc[m][n][2] + bb.z; v.w = acc[m][n][3] + bb.w;
      *reinterpret_cast<float4*>(&out[(size_t)row_o * DM + col_o]) = v;
    }
  }
}

// ---------------------------------------------------------------------------
extern "C" void kernel_launch(void* const* d_in, const int* in_sizes, int n_in,
                              void* d_out, int out_size, void* d_ws, size_t ws_size,
                              hipStream_t stream) {
  const float* x      = (const float*)d_in[0];
  const float* pre_w  = (const float*)d_in[1];
  const float* pre_b  = (const float*)d_in[2];
  const float* q_filt = (const float*)d_in[3];
  const float* k_filt = (const float*)d_in[4];
  const float* qp_w   = (const float*)d_in[5];
  const float* qp_b   = (const float*)d_in[6];
  const float* o_w    = (const float*)d_in[7];
  const float* o_b    = (const float*)d_in[8];
  const float* decay  = (const float*)d_in[9];
  float* out = (float*)d_out;

  char* ws = (char*)d_ws;
  unsigned short* Wt_hi = (unsigned short*)(ws);            // 128 KB
  unsigned short* Wt_lo = (unsigned short*)(ws + 131072);   // 128 KB
  float*    bias64 = (float*)(ws + 262144);                 // 256 B
  float*    Q0V    = (float*)(ws + 262400);                 // 8.39 MB -> ends 8651008
  float*    S      = (float*)(ws + 8651008);                // 1.08 MB -> ends 9732352
  unsigned short* owb = (unsigned short*)(ws + 9732352);    // 1.11 MB -> ends 10846464
  unsigned short* qpw_hi = (unsigned short*)(ws + 10846464);// 34.8 KB
  unsigned short* qpw_lo = (unsigned short*)(ws + 10881280);// 34.8 KB
  float*    qpb_pad = (float*)(ws + 10916096);              // 2.2 KB
  float*    Wp     = (float*)(ws + 16777216);               // 8.39 MB -> ends ~25.2 MB

  k_fold_part<<<dim3(NCHUNK, 16), dim3(256), 0, stream>>>(pre_w, q_filt, k_filt, Wp);
  k_foldred_bias<<<dim3(257), dim3(256), 0, stream>>>(Wp, pre_b, q_filt, k_filt, Wt_hi, Wt_lo, bias64);
  k_q0v_cs<<<dim3(MROWS / 64), dim3(512), 0, stream>>>(x, Wt_hi, Wt_lo, bias64, decay, Q0V, S);
  k_scanchunks<<<dim3(BATCH), dim3(576), 0, stream>>>(S);
  k_prep<<<dim3(NB_OWB + NB_QPW + 1), dim3(256), 0, stream>>>(o_w, qp_w, qp_b, owb, qpw_hi, qpw_lo, qpb_pad);
  k_out_fused<<<dim3(MROWS / 64), dim3(1024), 0, stream>>>(Q0V, S, qpw_hi, qpw_lo, qpb_pad, decay, owb, o_b, out);
}

// Round 18
// 173.606 us; speedup vs baseline: 1.1321x; 1.1321x over previous
//
#include <hip/hip_runtime.h>
#include <hip/hip_bf16.h>
#include <math.h>

#define T_SEQ   2048
#define DM      1024
#define KF      32
#define BATCH   16
#define CPDIM   528
#define KPAD    544               // CPDIM padded to 17*32 for the final GEMM
#define YSTR    552               // Y/Qe LDS row stride (halves)
#define MROWS   (BATCH * T_SEQ)   // 32768
#define NCHUNK  32
#define TCHUNK  64

typedef __bf16 bf16x8 __attribute__((ext_vector_type(8)));
typedef float f32x4 __attribute__((ext_vector_type(4)));
typedef unsigned uint2v __attribute__((ext_vector_type(2)));

// split v into bf16 hi (RNE) + bf16 lo (trunc of residual), packed (hi<<16)|lo
__device__ __forceinline__ unsigned packsplit(float v) {
  unsigned u = __float_as_uint(v);
  unsigned h = (u + 0x7fffu + ((u >> 16) & 1u)) & 0xffff0000u;
  float rr = v - __uint_as_float(h);
  return h | (__float_as_uint(rr) >> 16);
}

// RNE f32 -> bf16 (as u16)
__device__ __forceinline__ unsigned short f2bf(float f) {
  unsigned u = __float_as_uint(f);
  return (unsigned short)((u + 0x7fffu + ((u >> 16) & 1u)) >> 16);
}
__device__ __forceinline__ float bf2f(unsigned short h) {
  return __uint_as_float((unsigned)h << 16);
}

// async global->LDS, 16 bytes per lane (dest = wave-uniform base + lane*16)
__device__ __forceinline__ void gload16(const void* g, void* l) {
  __builtin_amdgcn_global_load_lds(
      (const __attribute__((address_space(1))) unsigned*)g,
      (__attribute__((address_space(3))) unsigned*)l, 16, 0, 0);
}

// ---------------------------------------------------------------------------
// Kernel 1a: split-K fold partials. Grid (32 s-chunks, 16 i-tiles).
// ---------------------------------------------------------------------------
__global__ __launch_bounds__(256) void k_fold_part(const float* __restrict__ pre_w,
                                                   const float* __restrict__ qf,
                                                   const float* __restrict__ kfil,
                                                   float* __restrict__ Wp) {
  const int sc = blockIdx.x;   // 0..31
  const int it = blockIdx.y;   // 0..15
  const int s0 = sc * 64, i0 = it * 64;
  const int tid = threadIdx.x;
  __shared__ float fs[64][64];
  __shared__ float ps[64][64];
  for (int idx = tid; idx < 4096; idx += 256) {
    const int s = idx >> 6, c = idx & 63;
    fs[s][c] = (c < KF) ? qf[(s0 + s) * KF + c] : kfil[(s0 + s) * KF + c - KF];
    ps[s][c] = pre_w[(size_t)(s0 + s) * DM + i0 + c];
  }
  __syncthreads();
  const int i = tid & 63;
  const int kb = tid >> 6;
  float acc[16] = {};
  for (int s = 0; s < 64; ++s) {
    const float pv = ps[s][i];
    const float4 f0 = *reinterpret_cast<const float4*>(&fs[s][kb * 16 + 0]);
    const float4 f1 = *reinterpret_cast<const float4*>(&fs[s][kb * 16 + 4]);
    const float4 f2 = *reinterpret_cast<const float4*>(&fs[s][kb * 16 + 8]);
    const float4 f3 = *reinterpret_cast<const float4*>(&fs[s][kb * 16 + 12]);
    acc[0]  = fmaf(pv, f0.x, acc[0]);  acc[1]  = fmaf(pv, f0.y, acc[1]);
    acc[2]  = fmaf(pv, f0.z, acc[2]);  acc[3]  = fmaf(pv, f0.w, acc[3]);
    acc[4]  = fmaf(pv, f1.x, acc[4]);  acc[5]  = fmaf(pv, f1.y, acc[5]);
    acc[6]  = fmaf(pv, f1.z, acc[6]);  acc[7]  = fmaf(pv, f1.w, acc[7]);
    acc[8]  = fmaf(pv, f2.x, acc[8]);  acc[9]  = fmaf(pv, f2.y, acc[9]);
    acc[10] = fmaf(pv, f2.z, acc[10]); acc[11] = fmaf(pv, f2.w, acc[11]);
    acc[12] = fmaf(pv, f3.x, acc[12]); acc[13] = fmaf(pv, f3.y, acc[13]);
    acc[14] = fmaf(pv, f3.z, acc[14]); acc[15] = fmaf(pv, f3.w, acc[15]);
  }
#pragma unroll
  for (int j = 0; j < 16; ++j)
    Wp[((size_t)sc * 64 + kb * 16 + j) * DM + i0 + i] = acc[j];
}

// ---------------------------------------------------------------------------
// Kernel 1b: reduce partials -> Wt hi/lo; block 256 does the bias fold.
// ---------------------------------------------------------------------------
__global__ __launch_bounds__(256) void k_foldred_bias(const float* __restrict__ Wp,
                                                      const float* __restrict__ pre_b,
                                                      const float* __restrict__ qf,
                                                      const float* __restrict__ kfil,
                                                      unsigned short* __restrict__ Wt_hi,
                                                      unsigned short* __restrict__ Wt_lo,
                                                      float* __restrict__ bias64) {
  if (blockIdx.x == 256) {
    __shared__ float part[4][64];
    const int k = threadIdx.x & 63;
    const int q = threadIdx.x >> 6;
    float acc = 0.f;
    for (int s = q * 512; s < (q + 1) * 512; ++s) {
      const float fv = (k < KF) ? qf[s * KF + k] : kfil[s * KF + k - KF];
      acc = fmaf(pre_b[s], fv, acc);
    }
    part[q][k] = acc;
    __syncthreads();
    if (threadIdx.x < 64)
      bias64[threadIdx.x] = part[0][k] + part[1][k] + part[2][k] + part[3][k];
    return;
  }
  const int idx = blockIdx.x * 256 + threadIdx.x;  // k*1024+i
  float acc = 0.f;
#pragma unroll
  for (int sc = 0; sc < NCHUNK; ++sc)
    acc += Wp[(size_t)sc * 64 * DM + idx];
  const unsigned pk = packsplit(acc);
  Wt_hi[idx] = (unsigned short)(pk >> 16);
  Wt_lo[idx] = (unsigned short)(pk & 0xffffu);
}

// ---------------------------------------------------------------------------
// Kernel 2: Q0V = x @ Wt^T + bias64 (3-term split MFMA) FUSED with per-chunk
// sums of Z.  8 waves, 3-buffer counted-vmcnt pipeline, K-skewed columns.
// (round-16 proven best)
// ---------------------------------------------------------------------------
__global__ __launch_bounds__(512) void k_q0v_cs(const float* __restrict__ x,
                                                const unsigned short* __restrict__ Wt_hi,
                                                const unsigned short* __restrict__ Wt_lo,
                                                const float* __restrict__ bias64,
                                                const float* __restrict__ decay,
                                                float* __restrict__ Q0V,
                                                float* __restrict__ S) {
  __shared__ float Xs[3][64 * 32];            // 24 KB
  __shared__ unsigned short Wh[3][64 * 32];   // 12 KB
  __shared__ unsigned short Wl[3][64 * 32];   // 12 KB
  __shared__ float vs2[64 * 32];              // 8 KB
  __shared__ float dec2[64];
  const int tid = threadIdx.x;
  const int m0 = blockIdx.x * 64;
  const int ph = blockIdx.x & 31;             // K-skew phase
  const int w = tid >> 6, l = tid & 63;
  const int g = l >> 4, r = l & 15;
  const int wr = w & 3, wh = w >> 2;          // row group / n half

  f32x4 acc[2] = {};

  auto kcol = [&](int i) { return ((i + ph) & 31) * 32; };

  auto stage = [&](int buf, int k0) {
    {
      const int row = tid >> 3, sl = tid & 7;
      const int col4 = (sl ^ (row & 7)) * 4;
      gload16(&x[(size_t)(m0 + row) * DM + k0 + col4], &Xs[buf][tid * 4]);
    }
    {
      const int c2 = tid & 255;
      const int row = c2 >> 2, sl = c2 & 3;
      const int colh = (sl ^ ((row >> 1) & 3)) * 8;
      unsigned short* dst = (tid < 256) ? &Wh[buf][c2 * 8] : &Wl[buf][c2 * 8];
      const unsigned short* src = (tid < 256) ? &Wt_hi[(size_t)row * DM + k0 + colh]
                                              : &Wt_lo[(size_t)row * DM + k0 + colh];
      gload16(src, dst);
    }
  };

  auto compute = [&](int cur) {
    const int arow = wr * 16 + r;
    const int sx = (2 * g) ^ (arow & 7);
    const int sy = (2 * g + 1) ^ (arow & 7);
    const f32x4 pX = *reinterpret_cast<const f32x4*>(&Xs[cur][arow * 32 + sx * 4]);
    const f32x4 pY = *reinterpret_cast<const f32x4*>(&Xs[cur][arow * 32 + sy * 4]);
    unsigned pk[8];
#pragma unroll
    for (int e = 0; e < 4; ++e) { pk[e] = packsplit(pX[e]); pk[4 + e] = packsplit(pY[e]); }
    union { unsigned u[4]; bf16x8 v; } ah, al;
#pragma unroll
    for (int j = 0; j < 4; ++j) {
      ah.u[j] = (pk[2 * j] >> 16) | (pk[2 * j + 1] & 0xffff0000u);
      al.u[j] = (pk[2 * j] & 0xffffu) | (pk[2 * j + 1] << 16);
    }
    bf16x8 bh[2], bl[2];
#pragma unroll
    for (int nb = 0; nb < 2; ++nb) {
      const int brow = (wh * 2 + nb) * 16 + r;
      const int bs = g ^ ((brow >> 1) & 3);
      const int off = brow * 32 + bs * 8;
      bh[nb] = *reinterpret_cast<const bf16x8*>(&Wh[cur][off]);
      bl[nb] = *reinterpret_cast<const bf16x8*>(&Wl[cur][off]);
    }
#pragma unroll
    for (int nb = 0; nb < 2; ++nb) {
      acc[nb] = __builtin_amdgcn_mfma_f32_16x16x32_bf16(bh[nb], ah.v, acc[nb], 0, 0, 0);
      acc[nb] = __builtin_amdgcn_mfma_f32_16x16x32_bf16(bh[nb], al.v, acc[nb], 0, 0, 0);
      acc[nb] = __builtin_amdgcn_mfma_f32_16x16x32_bf16(bl[nb], ah.v, acc[nb], 0, 0, 0);
    }
  };

  if (tid < 64) dec2[tid] = decay[(m0 & 2047) + tid];

  // prologue: 2 tiles in flight (4 outstanding loads/thread)
  stage(0, kcol(0));
  stage(1, kcol(1));

  for (int base = 0; base < 30; base += 3) {
#pragma unroll
    for (int sub = 0; sub < 3; ++sub) {
      const int it = base + sub;
      asm volatile("s_waitcnt vmcnt(2)" ::: "memory");   // oldest tile landed
      __builtin_amdgcn_s_barrier();
      __builtin_amdgcn_sched_barrier(0);
      stage((sub + 2) % 3, kcol(it + 2));                // keep depth 2
      compute(sub);
    }
  }
  asm volatile("s_waitcnt vmcnt(2)" ::: "memory");
  __builtin_amdgcn_s_barrier();
  __builtin_amdgcn_sched_barrier(0);
  compute(0);                                            // it = 30
  asm volatile("s_waitcnt vmcnt(0)" ::: "memory");
  __builtin_amdgcn_s_barrier();
  __builtin_amdgcn_sched_barrier(0);
  compute(1);                                            // it = 31

  // epilogue: write Q0V; stash V part (cols 32..63) in LDS for chunk sums
  const int trow = wr * 16 + r;
  const int row_o = m0 + trow;
#pragma unroll
  for (int nb = 0; nb < 2; ++nb) {
    const int n = wh * 2 + nb;
    const int col_o = n * 16 + g * 4;
    const float4 bb = *reinterpret_cast<const float4*>(&bias64[col_o]);
    float4 v;
    v.x = acc[nb][0] + bb.x; v.y = acc[nb][1] + bb.y;
    v.z = acc[nb][2] + bb.z; v.w = acc[nb][3] + bb.w;
    *reinterpret_cast<float4*>(&Q0V[(size_t)row_o * 64 + col_o]) = v;
    if (n >= 2)
      *reinterpret_cast<float4*>(&vs2[trow * 32 + (n - 2) * 16 + g * 4]) = v;
  }
  __syncthreads();

  const int b = m0 >> 11, ch = (m0 & 2047) >> 6;
#pragma unroll
  for (int pass = 0; pass < 2; ++pass) {
    const int c = tid + pass * 512;
    if (c < CPDIM) {
      int i = 0, rem = c;
      while (rem >= KF - i) { rem -= KF - i; ++i; }
      const int j = i + rem;
      const float sc = (i == j) ? 1.0f : 1.41421356237309515f;
      float h = 0.f;
#pragma unroll 4
      for (int t = 0; t < TCHUNK; ++t)
        h = fmaf(vs2[t * KF + i] * vs2[t * KF + j], dec2[t], h);
      S[(size_t)(b * NCHUNK + ch) * CPDIM + c] = h * sc;
    }
  }
}

// ---------------------------------------------------------------------------
// Kernel 3: prep (o_w/qp_w/qp_b) MERGED with chunk-sum exclusive scan.
// Blocks [0, NB_OWB): owb.  [NB_OWB, +NB_QPW): qpw.  next 1: qpb.
// last 16 blocks: per-batch exclusive scan of S (576 threads needed -> all
// blocks launched with 576; prep paths guard tid<256).
// ---------------------------------------------------------------------------
#define NB_OWB  (DM * KPAD / 256)           // 2176
#define NB_QPW  (KPAD * KF / 256)           // 68
#define NB_PREP (NB_OWB + NB_QPW + 1)
__global__ __launch_bounds__(576) void k_prep_scan(const float* __restrict__ ow,
                                                   const float* __restrict__ qp_w,
                                                   const float* __restrict__ qp_b,
                                                   unsigned short* __restrict__ owb,
                                                   unsigned short* __restrict__ qpw_hi,
                                                   unsigned short* __restrict__ qpw_lo,
                                                   float* __restrict__ qpb_pad,
                                                   float* __restrict__ S) {
  const int bx = blockIdx.x;
  const int tid = threadIdx.x;
  if (bx < NB_OWB) {
    if (tid >= 256) return;
    const int idx = bx * 256 + tid;
    const int n = idx / KPAD, k = idx - n * KPAD;
    owb[idx] = (k < CPDIM) ? f2bf(ow[(size_t)n * CPDIM + k]) : (unsigned short)0;
  } else if (bx < NB_OWB + NB_QPW) {
    if (tid >= 256) return;
    const int idx = (bx - NB_OWB) * 256 + tid;   // c*32+q
    const int c = idx >> 5;
    unsigned pk = 0;
    if (c < CPDIM) pk = packsplit(qp_w[idx]);
    qpw_hi[idx] = (unsigned short)(pk >> 16);
    qpw_lo[idx] = (unsigned short)(pk & 0xffffu);
  } else if (bx < NB_PREP) {
    if (tid >= 256) return;
    for (int c = tid; c < KPAD; c += 256)
      qpb_pad[c] = (c < CPDIM) ? qp_b[c] : 0.f;
  } else {
    const int b = bx - NB_PREP;                  // 0..15
    const int c = tid;
    if (c >= CPDIM) return;
    float v[NCHUNK];
#pragma unroll
    for (int ch = 0; ch < NCHUNK; ++ch)
      v[ch] = S[(size_t)(b * NCHUNK + ch) * CPDIM + c];
    float run = 0.f;
#pragma unroll
    for (int ch = 0; ch < NCHUNK; ++ch) {
      S[(size_t)(b * NCHUNK + ch) * CPDIM + c] = run;
      run += v[ch];
    }
  }
}

// ---------------------------------------------------------------------------
// Kernel 4: FUSED chunk pipeline, 16 waves, LDS = Ylds only; phase-2 owb
// register double-buffer.  (round-16 proven best)
// ---------------------------------------------------------------------------
__global__ __launch_bounds__(1024, 4) void k_out_fused(const float* __restrict__ Q0V,
                                                       const float* __restrict__ S,
                                                       const unsigned short* __restrict__ qpw_hi,
                                                       const unsigned short* __restrict__ qpw_lo,
                                                       const float* __restrict__ qpb_pad,
                                                       const float* __restrict__ decay,
                                                       const unsigned short* __restrict__ owb,
                                                       const float* __restrict__ ob,
                                                       float* __restrict__ out) {
  __shared__ unsigned short Ylds[64 * YSTR];   // 69 KB (Qe, then Y in place)
  const int tid = threadIdx.x;
  const int m0 = blockIdx.x * 64;
  const int b = m0 >> 11, ch = (m0 & 2047) >> 6;
  const int t0 = m0 & 2047;
  const int wv = tid >> 6, l = tid & 63;
  const int g = l >> 4, r = l & 15;

  // ---- phase 1a: Qe = qp_b + Q0 @ qp_w^T; A-frags straight from global ----
  {
    bf16x8 qah[4], qal[4];
#pragma unroll
    for (int m = 0; m < 4; ++m) {
      const int t = m * 16 + r;
      const f32x4 x0 = *reinterpret_cast<const f32x4*>(&Q0V[(size_t)(m0 + t) * 64 + g * 8]);
      const f32x4 x1 = *reinterpret_cast<const f32x4*>(&Q0V[(size_t)(m0 + t) * 64 + g * 8 + 4]);
      unsigned pk[8];
#pragma unroll
      for (int e = 0; e < 4; ++e) { pk[e] = packsplit(x0[e]); pk[4 + e] = packsplit(x1[e]); }
      union { unsigned u[4]; bf16x8 v; } hh, ll;
#pragma unroll
      for (int j = 0; j < 4; ++j) {
        hh.u[j] = (pk[2 * j] >> 16) | (pk[2 * j + 1] & 0xffff0000u);
        ll.u[j] = (pk[2 * j] & 0xffffu) | (pk[2 * j + 1] << 16);
      }
      qah[m] = hh.v; qal[m] = ll.v;
    }
    for (int nt = wv; nt < KPAD / 16; nt += 16) {
      const int crow = nt * 16 + r;
      const bf16x8 bh = *reinterpret_cast<const bf16x8*>(&qpw_hi[crow * KF + g * 8]);
      const bf16x8 bl = *reinterpret_cast<const bf16x8*>(&qpw_lo[crow * KF + g * 8]);
      const int cbase = nt * 16 + g * 4;
      const float4 qb4 = *reinterpret_cast<const float4*>(&qpb_pad[cbase]);
      f32x4 a[4];
#pragma unroll
      for (int m = 0; m < 4; ++m) { a[m][0] = qb4.x; a[m][1] = qb4.y; a[m][2] = qb4.z; a[m][3] = qb4.w; }
#pragma unroll
      for (int m = 0; m < 4; ++m) {
        a[m] = __builtin_amdgcn_mfma_f32_16x16x32_bf16(bh, qah[m], a[m], 0, 0, 0);
        a[m] = __builtin_amdgcn_mfma_f32_16x16x32_bf16(bh, qal[m], a[m], 0, 0, 0);
        a[m] = __builtin_amdgcn_mfma_f32_16x16x32_bf16(bl, qah[m], a[m], 0, 0, 0);
      }
#pragma unroll
      for (int m = 0; m < 4; ++m) {
        const int t = m * 16 + r;
        union { unsigned short s[4]; unsigned u[2]; } pk4;
#pragma unroll
        for (int j = 0; j < 4; ++j) pk4.s[j] = f2bf(a[m][j]);
        *reinterpret_cast<uint2v*>(&Ylds[t * YSTR + cbase]) = uint2v{pk4.u[0], pk4.u[1]};
      }
    }
  }
  __syncthreads();

  // ---- phase 1b: Y[t][c] = Qe[t][c] * H[t][c]; V from global Q0V tile ----
  if (tid < CPDIM) {
    const int c = tid;
    int i = 0, rem = c;
    while (rem >= KF - i) { rem -= KF - i; ++i; }
    const int j = i + rem;
    const float sc = (i == j) ? 1.0f : 1.41421356237309515f;
    const float* vrow = &Q0V[(size_t)m0 * 64 + 32];
    float h = S[(size_t)(b * NCHUNK + ch) * CPDIM + c];
#pragma unroll 8
    for (int t = 0; t < TCHUNK; ++t) {
      const float vi = vrow[t * 64 + i];
      const float vj = vrow[t * 64 + j];
      h = fmaf(vi * vj * sc, decay[t0 + t], h);
      const float qv = bf2f(Ylds[t * YSTR + c]);
      Ylds[t * YSTR + c] = f2bf(qv * h);
    }
  }
  __syncthreads();

  // ---- phase 2: out[m0..m0+63][:] = Y @ owb^T + ob; wave -> 64 cols ----
  f32x4 acc[4][4] = {};
  bf16x8 bfA[4], bfB[4];

  auto loadB = [&](bf16x8 (&dst)[4], int ks) {
    const int kh = ks * 32 + g * 8;
#pragma unroll
    for (int n = 0; n < 4; ++n)
      dst[n] = *reinterpret_cast<const bf16x8*>(&owb[(size_t)(wv * 64 + n * 16 + r) * KPAD + kh]);
  };
  auto step = [&](const bf16x8 (&bc)[4], int ks) {
    const int kh = ks * 32 + g * 8;
    bf16x8 af[4];
#pragma unroll
    for (int m = 0; m < 4; ++m)
      af[m] = *reinterpret_cast<const bf16x8*>(&Ylds[(m * 16 + r) * YSTR + kh]);
#pragma unroll
    for (int m = 0; m < 4; ++m)
#pragma unroll
      for (int n = 0; n < 4; ++n)
        acc[m][n] = __builtin_amdgcn_mfma_f32_16x16x32_bf16(bc[n], af[m], acc[m][n], 0, 0, 0);
  };

  loadB(bfA, 0);
#pragma unroll
  for (int ks = 0; ks < 16; ks += 2) {
    loadB(bfB, ks + 1);
    step(bfA, ks);
    loadB(bfA, ks + 2);   // ks+2 <= 16, valid
    step(bfB, ks + 1);
  }
  step(bfA, 16);

  // D row-idx(g*4+j) <-> owb side (out col), col-idx(r) <-> Y side (out row)
#pragma unroll
  for (int m = 0; m < 4; ++m) {
    const int row_o = m0 + m * 16 + r;
#pragma unroll
    for (int n = 0; n < 4; ++n) {
      const int col_o = wv * 64 + n * 16 + g * 4;
      const float4 bb = *reinterpret_cast<const float4*>(&ob[col_o]);
      float4 v;
      v.x = acc[m][n][0] + bb.x; v.y = acc[m][n][1] + bb.y;
      v.z = acc[m][n][2] + bb.z; v.w = acc[m][n][3] + bb.w;
      *reinterpret_cast<float4*>(&out[(size_t)row_o * DM + col_o]) = v;
    }
  }
}

// ---------------------------------------------------------------------------
extern "C" void kernel_launch(void* const* d_in, const int* in_sizes, int n_in,
                              void* d_out, int out_size, void* d_ws, size_t ws_size,
                              hipStream_t stream) {
  const float* x      = (const float*)d_in[0];
  const float* pre_w  = (const float*)d_in[1];
  const float* pre_b  = (const float*)d_in[2];
  const float* q_filt = (const float*)d_in[3];
  const float* k_filt = (const float*)d_in[4];
  const float* qp_w   = (const float*)d_in[5];
  const float* qp_b   = (const float*)d_in[6];
  const float* o_w    = (const float*)d_in[7];
  const float* o_b    = (const float*)d_in[8];
  const float* decay  = (const float*)d_in[9];
  float* out = (float*)d_out;

  char* ws = (char*)d_ws;
  unsigned short* Wt_hi = (unsigned short*)(ws);            // 128 KB
  unsigned short* Wt_lo = (unsigned short*)(ws + 131072);   // 128 KB
  float*    bias64 = (float*)(ws + 262144);                 // 256 B
  float*    Q0V    = (float*)(ws + 262400);                 // 8.39 MB -> ends 8651008
  float*    S      = (float*)(ws + 8651008);                // 1.08 MB -> ends 9732352
  unsigned short* owb = (unsigned short*)(ws + 9732352);    // 1.11 MB -> ends 10846464
  unsigned short* qpw_hi = (unsigned short*)(ws + 10846464);// 34.8 KB
  unsigned short* qpw_lo = (unsigned short*)(ws + 10881280);// 34.8 KB
  float*    qpb_pad = (float*)(ws + 10916096);              // 2.2 KB
  float*    Wp     = (float*)(ws + 16777216);               // 8.39 MB -> ends ~25.2 MB

  k_fold_part<<<dim3(NCHUNK, 16), dim3(256), 0, stream>>>(pre_w, q_filt, k_filt, Wp);
  k_foldred_bias<<<dim3(257), dim3(256), 0, stream>>>(Wp, pre_b, q_filt, k_filt, Wt_hi, Wt_lo, bias64);
  k_q0v_cs<<<dim3(MROWS / 64), dim3(512), 0, stream>>>(x, Wt_hi, Wt_lo, bias64, decay, Q0V, S);
  k_prep_scan<<<dim3(NB_PREP + BATCH), dim3(576), 0, stream>>>(o_w, qp_w, qp_b, owb, qpw_hi, qpw_lo, qpb_pad, S);
  k_out_fused<<<dim3(MROWS / 64), dim3(1024), 0, stream>>>(Q0V, S, qpw_hi, qpw_lo, qpb_pad, decay, owb, o_b, out);
}

// Round 20
// 171.682 us; speedup vs baseline: 1.1448x; 1.0112x over previous
//
#include <hip/hip_runtime.h>
#include <hip/hip_bf16.h>
#include <math.h>

#define T_SEQ   2048
#define DM      1024
#define KF      32
#define BATCH   16
#define CPDIM   528
#define KPAD    544               // CPDIM padded to 17*32 for the final GEMM
#define YSTR    552               // Y/Qe LDS row stride (halves)
#define MROWS   (BATCH * T_SEQ)   // 32768
#define NCHUNK  32
#define TCHUNK  64

typedef __bf16 bf16x8 __attribute__((ext_vector_type(8)));
typedef float f32x4 __attribute__((ext_vector_type(4)));
typedef unsigned uint2v __attribute__((ext_vector_type(2)));

// split v into bf16 hi (RNE) + bf16 lo (trunc of residual), packed (hi<<16)|lo
__device__ __forceinline__ unsigned packsplit(float v) {
  unsigned u = __float_as_uint(v);
  unsigned h = (u + 0x7fffu + ((u >> 16) & 1u)) & 0xffff0000u;
  float rr = v - __uint_as_float(h);
  return h | (__float_as_uint(rr) >> 16);
}

// RNE f32 -> bf16 (as u16)
__device__ __forceinline__ unsigned short f2bf(float f) {
  unsigned u = __float_as_uint(f);
  return (unsigned short)((u + 0x7fffu + ((u >> 16) & 1u)) >> 16);
}
__device__ __forceinline__ float bf2f(unsigned short h) {
  return __uint_as_float((unsigned)h << 16);
}

// async global->LDS, 16 bytes per lane (dest = wave-uniform base + lane*16)
__device__ __forceinline__ void gload16(const void* g, void* l) {
  __builtin_amdgcn_global_load_lds(
      (const __attribute__((address_space(1))) unsigned*)g,
      (__attribute__((address_space(3))) unsigned*)l, 16, 0, 0);
}

// ---------------------------------------------------------------------------
// Kernel 1a: split-K fold partials. Grid (32 s-chunks, 16 i-tiles).
// ---------------------------------------------------------------------------
__global__ __launch_bounds__(256) void k_fold_part(const float* __restrict__ pre_w,
                                                   const float* __restrict__ qf,
                                                   const float* __restrict__ kfil,
                                                   float* __restrict__ Wp) {
  const int sc = blockIdx.x;   // 0..31
  const int it = blockIdx.y;   // 0..15
  const int s0 = sc * 64, i0 = it * 64;
  const int tid = threadIdx.x;
  __shared__ float fs[64][64];
  __shared__ float ps[64][64];
  for (int idx = tid; idx < 4096; idx += 256) {
    const int s = idx >> 6, c = idx & 63;
    fs[s][c] = (c < KF) ? qf[(s0 + s) * KF + c] : kfil[(s0 + s) * KF + c - KF];
    ps[s][c] = pre_w[(size_t)(s0 + s) * DM + i0 + c];
  }
  __syncthreads();
  const int i = tid & 63;
  const int kb = tid >> 6;
  float acc[16] = {};
  for (int s = 0; s < 64; ++s) {
    const float pv = ps[s][i];
    const float4 f0 = *reinterpret_cast<const float4*>(&fs[s][kb * 16 + 0]);
    const float4 f1 = *reinterpret_cast<const float4*>(&fs[s][kb * 16 + 4]);
    const float4 f2 = *reinterpret_cast<const float4*>(&fs[s][kb * 16 + 8]);
    const float4 f3 = *reinterpret_cast<const float4*>(&fs[s][kb * 16 + 12]);
    acc[0]  = fmaf(pv, f0.x, acc[0]);  acc[1]  = fmaf(pv, f0.y, acc[1]);
    acc[2]  = fmaf(pv, f0.z, acc[2]);  acc[3]  = fmaf(pv, f0.w, acc[3]);
    acc[4]  = fmaf(pv, f1.x, acc[4]);  acc[5]  = fmaf(pv, f1.y, acc[5]);
    acc[6]  = fmaf(pv, f1.z, acc[6]);  acc[7]  = fmaf(pv, f1.w, acc[7]);
    acc[8]  = fmaf(pv, f2.x, acc[8]);  acc[9]  = fmaf(pv, f2.y, acc[9]);
    acc[10] = fmaf(pv, f2.z, acc[10]); acc[11] = fmaf(pv, f2.w, acc[11]);
    acc[12] = fmaf(pv, f3.x, acc[12]); acc[13] = fmaf(pv, f3.y, acc[13]);
    acc[14] = fmaf(pv, f3.z, acc[14]); acc[15] = fmaf(pv, f3.w, acc[15]);
  }
#pragma unroll
  for (int j = 0; j < 16; ++j)
    Wp[((size_t)sc * 64 + kb * 16 + j) * DM + i0 + i] = acc[j];
}

// ---------------------------------------------------------------------------
// Kernel 1b: reduce partials -> Wt hi/lo; block 256 does the bias fold.
// ---------------------------------------------------------------------------
__global__ __launch_bounds__(256) void k_foldred_bias(const float* __restrict__ Wp,
                                                      const float* __restrict__ pre_b,
                                                      const float* __restrict__ qf,
                                                      const float* __restrict__ kfil,
                                                      unsigned short* __restrict__ Wt_hi,
                                                      unsigned short* __restrict__ Wt_lo,
                                                      float* __restrict__ bias64) {
  if (blockIdx.x == 256) {
    __shared__ float part[4][64];
    const int k = threadIdx.x & 63;
    const int q = threadIdx.x >> 6;
    float acc = 0.f;
    for (int s = q * 512; s < (q + 1) * 512; ++s) {
      const float fv = (k < KF) ? qf[s * KF + k] : kfil[s * KF + k - KF];
      acc = fmaf(pre_b[s], fv, acc);
    }
    part[q][k] = acc;
    __syncthreads();
    if (threadIdx.x < 64)
      bias64[threadIdx.x] = part[0][k] + part[1][k] + part[2][k] + part[3][k];
    return;
  }
  const int idx = blockIdx.x * 256 + threadIdx.x;  // k*1024+i
  float acc = 0.f;
#pragma unroll
  for (int sc = 0; sc < NCHUNK; ++sc)
    acc += Wp[(size_t)sc * 64 * DM + idx];
  const unsigned pk = packsplit(acc);
  Wt_hi[idx] = (unsigned short)(pk >> 16);
  Wt_lo[idx] = (unsigned short)(pk & 0xffffu);
}

// ---------------------------------------------------------------------------
// Kernel 2: Q0V = x @ Wt^T + bias64 (3-term split MFMA) FUSED with per-chunk
// sums of Z.  8 waves, 3-buffer counted-vmcnt pipeline, K-skewed columns.
// ---------------------------------------------------------------------------
__global__ __launch_bounds__(512) void k_q0v_cs(const float* __restrict__ x,
                                                const unsigned short* __restrict__ Wt_hi,
                                                const unsigned short* __restrict__ Wt_lo,
                                                const float* __restrict__ bias64,
                                                const float* __restrict__ decay,
                                                float* __restrict__ Q0V,
                                                float* __restrict__ S) {
  __shared__ float Xs[3][64 * 32];            // 24 KB
  __shared__ unsigned short Wh[3][64 * 32];   // 12 KB
  __shared__ unsigned short Wl[3][64 * 32];   // 12 KB
  __shared__ float vs2[64 * 32];              // 8 KB
  __shared__ float dec2[64];
  const int tid = threadIdx.x;
  const int m0 = blockIdx.x * 64;
  const int ph = blockIdx.x & 31;             // K-skew phase
  const int w = tid >> 6, l = tid & 63;
  const int g = l >> 4, r = l & 15;
  const int wr = w & 3, wh = w >> 2;          // row group / n half

  f32x4 acc[2] = {};

  auto kcol = [&](int i) { return ((i + ph) & 31) * 32; };

  auto stage = [&](int buf, int k0) {
    {
      const int row = tid >> 3, sl = tid & 7;
      const int col4 = (sl ^ (row & 7)) * 4;
      gload16(&x[(size_t)(m0 + row) * DM + k0 + col4], &Xs[buf][tid * 4]);
    }
    {
      const int c2 = tid & 255;
      const int row = c2 >> 2, sl = c2 & 3;
      const int colh = (sl ^ ((row >> 1) & 3)) * 8;
      unsigned short* dst = (tid < 256) ? &Wh[buf][c2 * 8] : &Wl[buf][c2 * 8];
      const unsigned short* src = (tid < 256) ? &Wt_hi[(size_t)row * DM + k0 + colh]
                                              : &Wt_lo[(size_t)row * DM + k0 + colh];
      gload16(src, dst);
    }
  };

  auto compute = [&](int cur) {
    const int arow = wr * 16 + r;
    const int sx = (2 * g) ^ (arow & 7);
    const int sy = (2 * g + 1) ^ (arow & 7);
    const f32x4 pX = *reinterpret_cast<const f32x4*>(&Xs[cur][arow * 32 + sx * 4]);
    const f32x4 pY = *reinterpret_cast<const f32x4*>(&Xs[cur][arow * 32 + sy * 4]);
    unsigned pk[8];
#pragma unroll
    for (int e = 0; e < 4; ++e) { pk[e] = packsplit(pX[e]); pk[4 + e] = packsplit(pY[e]); }
    union { unsigned u[4]; bf16x8 v; } ah, al;
#pragma unroll
    for (int j = 0; j < 4; ++j) {
      ah.u[j] = (pk[2 * j] >> 16) | (pk[2 * j + 1] & 0xffff0000u);
      al.u[j] = (pk[2 * j] & 0xffffu) | (pk[2 * j + 1] << 16);
    }
    bf16x8 bh[2], bl[2];
#pragma unroll
    for (int nb = 0; nb < 2; ++nb) {
      const int brow = (wh * 2 + nb) * 16 + r;
      const int bs = g ^ ((brow >> 1) & 3);
      const int off = brow * 32 + bs * 8;
      bh[nb] = *reinterpret_cast<const bf16x8*>(&Wh[cur][off]);
      bl[nb] = *reinterpret_cast<const bf16x8*>(&Wl[cur][off]);
    }
#pragma unroll
    for (int nb = 0; nb < 2; ++nb) {
      acc[nb] = __builtin_amdgcn_mfma_f32_16x16x32_bf16(bh[nb], ah.v, acc[nb], 0, 0, 0);
      acc[nb] = __builtin_amdgcn_mfma_f32_16x16x32_bf16(bh[nb], al.v, acc[nb], 0, 0, 0);
      acc[nb] = __builtin_amdgcn_mfma_f32_16x16x32_bf16(bl[nb], ah.v, acc[nb], 0, 0, 0);
    }
  };

  if (tid < 64) dec2[tid] = decay[(m0 & 2047) + tid];

  // prologue: 2 tiles in flight (4 outstanding loads/thread)
  stage(0, kcol(0));
  stage(1, kcol(1));

  for (int base = 0; base < 30; base += 3) {
#pragma unroll
    for (int sub = 0; sub < 3; ++sub) {
      const int it = base + sub;
      asm volatile("s_waitcnt vmcnt(2)" ::: "memory");   // oldest tile landed
      __builtin_amdgcn_s_barrier();
      __builtin_amdgcn_sched_barrier(0);
      stage((sub + 2) % 3, kcol(it + 2));                // keep depth 2
      compute(sub);
    }
  }
  asm volatile("s_waitcnt vmcnt(2)" ::: "memory");
  __builtin_amdgcn_s_barrier();
  __builtin_amdgcn_sched_barrier(0);
  compute(0);                                            // it = 30
  asm volatile("s_waitcnt vmcnt(0)" ::: "memory");
  __builtin_amdgcn_s_barrier();
  __builtin_amdgcn_sched_barrier(0);
  compute(1);                                            // it = 31

  // epilogue: write Q0V; stash V part (cols 32..63) in LDS for chunk sums
  const int trow = wr * 16 + r;
  const int row_o = m0 + trow;
#pragma unroll
  for (int nb = 0; nb < 2; ++nb) {
    const int n = wh * 2 + nb;
    const int col_o = n * 16 + g * 4;
    const float4 bb = *reinterpret_cast<const float4*>(&bias64[col_o]);
    float4 v;
    v.x = acc[nb][0] + bb.x; v.y = acc[nb][1] + bb.y;
    v.z = acc[nb][2] + bb.z; v.w = acc[nb][3] + bb.w;
    *reinterpret_cast<float4*>(&Q0V[(size_t)row_o * 64 + col_o]) = v;
    if (n >= 2)
      *reinterpret_cast<float4*>(&vs2[trow * 32 + (n - 2) * 16 + g * 4]) = v;
  }
  __syncthreads();

  const int b = m0 >> 11, ch = (m0 & 2047) >> 6;
#pragma unroll
  for (int pass = 0; pass < 2; ++pass) {
    const int c = tid + pass * 512;
    if (c < CPDIM) {
      int i = 0, rem = c;
      while (rem >= KF - i) { rem -= KF - i; ++i; }
      const int j = i + rem;
      const float sc = (i == j) ? 1.0f : 1.41421356237309515f;
      float h = 0.f;
#pragma unroll 4
      for (int t = 0; t < TCHUNK; ++t)
        h = fmaf(vs2[t * KF + i] * vs2[t * KF + j], dec2[t], h);
      S[(size_t)(b * NCHUNK + ch) * CPDIM + c] = h * sc;
    }
  }
}

// ---------------------------------------------------------------------------
// Kernel 3: prep (o_w/qp_w/qp_b) MERGED with chunk-sum exclusive scan.
// ---------------------------------------------------------------------------
#define NB_OWB  (DM * KPAD / 256)           // 2176
#define NB_QPW  (KPAD * KF / 256)           // 68
#define NB_PREP (NB_OWB + NB_QPW + 1)
__global__ __launch_bounds__(576) void k_prep_scan(const float* __restrict__ ow,
                                                   const float* __restrict__ qp_w,
                                                   const float* __restrict__ qp_b,
                                                   unsigned short* __restrict__ owb,
                                                   unsigned short* __restrict__ qpw_hi,
                                                   unsigned short* __restrict__ qpw_lo,
                                                   float* __restrict__ qpb_pad,
                                                   float* __restrict__ S) {
  const int bx = blockIdx.x;
  const int tid = threadIdx.x;
  if (bx < NB_OWB) {
    if (tid >= 256) return;
    const int idx = bx * 256 + tid;
    const int n = idx / KPAD, k = idx - n * KPAD;
    owb[idx] = (k < CPDIM) ? f2bf(ow[(size_t)n * CPDIM + k]) : (unsigned short)0;
  } else if (bx < NB_OWB + NB_QPW) {
    if (tid >= 256) return;
    const int idx = (bx - NB_OWB) * 256 + tid;   // c*32+q
    const int c = idx >> 5;
    unsigned pk = 0;
    if (c < CPDIM) pk = packsplit(qp_w[idx]);
    qpw_hi[idx] = (unsigned short)(pk >> 16);
    qpw_lo[idx] = (unsigned short)(pk & 0xffffu);
  } else if (bx < NB_PREP) {
    if (tid >= 256) return;
    for (int c = tid; c < KPAD; c += 256)
      qpb_pad[c] = (c < CPDIM) ? qp_b[c] : 0.f;
  } else {
    const int b = bx - NB_PREP;                  // 0..15
    const int c = tid;
    if (c >= CPDIM) return;
    float v[NCHUNK];
#pragma unroll
    for (int ch = 0; ch < NCHUNK; ++ch)
      v[ch] = S[(size_t)(b * NCHUNK + ch) * CPDIM + c];
    float run = 0.f;
#pragma unroll
    for (int ch = 0; ch < NCHUNK; ++ch) {
      S[(size_t)(b * NCHUNK + ch) * CPDIM + c] = run;
      run += v[ch];
    }
  }
}

// ---------------------------------------------------------------------------
// Kernel 4: FUSED chunk pipeline, 16 waves, LDS = Ylds only; phase-2 owb
// register double-buffer.  Non-temporal out stores (f32x4 ext-vector form)
// so the 134 MB write stream does not thrash L2.
// ---------------------------------------------------------------------------
__global__ __launch_bounds__(1024, 4) void k_out_fused(const float* __restrict__ Q0V,
                                                       const float* __restrict__ S,
                                                       const unsigned short* __restrict__ qpw_hi,
                                                       const unsigned short* __restrict__ qpw_lo,
                                                       const float* __restrict__ qpb_pad,
                                                       const float* __restrict__ decay,
                                                       const unsigned short* __restrict__ owb,
                                                       const float* __restrict__ ob,
                                                       float* __restrict__ out) {
  __shared__ unsigned short Ylds[64 * YSTR];   // 69 KB (Qe, then Y in place)
  const int tid = threadIdx.x;
  const int m0 = blockIdx.x * 64;
  const int b = m0 >> 11, ch = (m0 & 2047) >> 6;
  const int t0 = m0 & 2047;
  const int wv = tid >> 6, l = tid & 63;
  const int g = l >> 4, r = l & 15;

  // ---- phase 1a: Qe = qp_b + Q0 @ qp_w^T; A-frags straight from global ----
  {
    bf16x8 qah[4], qal[4];
#pragma unroll
    for (int m = 0; m < 4; ++m) {
      const int t = m * 16 + r;
      const f32x4 x0 = *reinterpret_cast<const f32x4*>(&Q0V[(size_t)(m0 + t) * 64 + g * 8]);
      const f32x4 x1 = *reinterpret_cast<const f32x4*>(&Q0V[(size_t)(m0 + t) * 64 + g * 8 + 4]);
      unsigned pk[8];
#pragma unroll
      for (int e = 0; e < 4; ++e) { pk[e] = packsplit(x0[e]); pk[4 + e] = packsplit(x1[e]); }
      union { unsigned u[4]; bf16x8 v; } hh, ll;
#pragma unroll
      for (int j = 0; j < 4; ++j) {
        hh.u[j] = (pk[2 * j] >> 16) | (pk[2 * j + 1] & 0xffff0000u);
        ll.u[j] = (pk[2 * j] & 0xffffu) | (pk[2 * j + 1] << 16);
      }
      qah[m] = hh.v; qal[m] = ll.v;
    }
    for (int nt = wv; nt < KPAD / 16; nt += 16) {
      const int crow = nt * 16 + r;
      const bf16x8 bh = *reinterpret_cast<const bf16x8*>(&qpw_hi[crow * KF + g * 8]);
      const bf16x8 bl = *reinterpret_cast<const bf16x8*>(&qpw_lo[crow * KF + g * 8]);
      const int cbase = nt * 16 + g * 4;
      const float4 qb4 = *reinterpret_cast<const float4*>(&qpb_pad[cbase]);
      f32x4 a[4];
#pragma unroll
      for (int m = 0; m < 4; ++m) { a[m][0] = qb4.x; a[m][1] = qb4.y; a[m][2] = qb4.z; a[m][3] = qb4.w; }
#pragma unroll
      for (int m = 0; m < 4; ++m) {
        a[m] = __builtin_amdgcn_mfma_f32_16x16x32_bf16(bh, qah[m], a[m], 0, 0, 0);
        a[m] = __builtin_amdgcn_mfma_f32_16x16x32_bf16(bh, qal[m], a[m], 0, 0, 0);
        a[m] = __builtin_amdgcn_mfma_f32_16x16x32_bf16(bl, qah[m], a[m], 0, 0, 0);
      }
#pragma unroll
      for (int m = 0; m < 4; ++m) {
        const int t = m * 16 + r;
        union { unsigned short s[4]; unsigned u[2]; } pk4;
#pragma unroll
        for (int j = 0; j < 4; ++j) pk4.s[j] = f2bf(a[m][j]);
        *reinterpret_cast<uint2v*>(&Ylds[t * YSTR + cbase]) = uint2v{pk4.u[0], pk4.u[1]};
      }
    }
  }
  __syncthreads();

  // ---- phase 1b: Y[t][c] = Qe[t][c] * H[t][c]; V from global Q0V tile ----
  if (tid < CPDIM) {
    const int c = tid;
    int i = 0, rem = c;
    while (rem >= KF - i) { rem -= KF - i; ++i; }
    const int j = i + rem;
    const float sc = (i == j) ? 1.0f : 1.41421356237309515f;
    const float* vrow = &Q0V[(size_t)m0 * 64 + 32];
    float h = S[(size_t)(b * NCHUNK + ch) * CPDIM + c];
#pragma unroll 8
    for (int t = 0; t < TCHUNK; ++t) {
      const float vi = vrow[t * 64 + i];
      const float vj = vrow[t * 64 + j];
      h = fmaf(vi * vj * sc, decay[t0 + t], h);
      const float qv = bf2f(Ylds[t * YSTR + c]);
      Ylds[t * YSTR + c] = f2bf(qv * h);
    }
  }
  __syncthreads();

  // ---- phase 2: out[m0..m0+63][:] = Y @ owb^T + ob; wave -> 64 cols ----
  f32x4 acc[4][4] = {};
  bf16x8 bfA[4], bfB[4];

  auto loadB = [&](bf16x8 (&dst)[4], int ks) {
    const int kh = ks * 32 + g * 8;
#pragma unroll
    for (int n = 0; n < 4; ++n)
      dst[n] = *reinterpret_cast<const bf16x8*>(&owb[(size_t)(wv * 64 + n * 16 + r) * KPAD + kh]);
  };
  auto step = [&](const bf16x8 (&bc)[4], int ks) {
    const int kh = ks * 32 + g * 8;
    bf16x8 af[4];
#pragma unroll
    for (int m = 0; m < 4; ++m)
      af[m] = *reinterpret_cast<const bf16x8*>(&Ylds[(m * 16 + r) * YSTR + kh]);
#pragma unroll
    for (int m = 0; m < 4; ++m)
#pragma unroll
      for (int n = 0; n < 4; ++n)
        acc[m][n] = __builtin_amdgcn_mfma_f32_16x16x32_bf16(bc[n], af[m], acc[m][n], 0, 0, 0);
  };

  loadB(bfA, 0);
#pragma unroll
  for (int ks = 0; ks < 16; ks += 2) {
    loadB(bfB, ks + 1);
    step(bfA, ks);
    loadB(bfA, ks + 2);   // ks+2 <= 16, valid
    step(bfB, ks + 1);
  }
  step(bfA, 16);

  // D row-idx(g*4+j) <-> owb side (out col), col-idx(r) <-> Y side (out row)
  // Non-temporal stores (ext-vector f32x4): keep the write stream out of L2.
#pragma unroll
  for (int m = 0; m < 4; ++m) {
    const int row_o = m0 + m * 16 + r;
#pragma unroll
    for (int n = 0; n < 4; ++n) {
      const int col_o = wv * 64 + n * 16 + g * 4;
      const float4 bb = *reinterpret_cast<const float4*>(&ob[col_o]);
      f32x4 v;
      v[0] = acc[m][n][0] + bb.x; v[1] = acc[m][n][1] + bb.y;
      v[2] = acc[m][n][2] + bb.z; v[3] = acc[m][n][3] + bb.w;
      __builtin_nontemporal_store(v, reinterpret_cast<f32x4*>(&out[(size_t)row_o * DM + col_o]));
    }
  }
}

// ---------------------------------------------------------------------------
extern "C" void kernel_launch(void* const* d_in, const int* in_sizes, int n_in,
                              void* d_out, int out_size, void* d_ws, size_t ws_size,
                              hipStream_t stream) {
  const float* x      = (const float*)d_in[0];
  const float* pre_w  = (const float*)d_in[1];
  const float* pre_b  = (const float*)d_in[2];
  const float* q_filt = (const float*)d_in[3];
  const float* k_filt = (const float*)d_in[4];
  const float* qp_w   = (const float*)d_in[5];
  const float* qp_b   = (const float*)d_in[6];
  const float* o_w    = (const float*)d_in[7];
  const float* o_b    = (const float*)d_in[8];
  const float* decay  = (const float*)d_in[9];
  float* out = (float*)d_out;

  char* ws = (char*)d_ws;
  unsigned short* Wt_hi = (unsigned short*)(ws);            // 128 KB
  unsigned short* Wt_lo = (unsigned short*)(ws + 131072);   // 128 KB
  float*    bias64 = (float*)(ws + 262144);                 // 256 B
  float*    Q0V    = (float*)(ws + 262400);                 // 8.39 MB -> ends 8651008
  float*    S      = (float*)(ws + 8651008);                // 1.08 MB -> ends 9732352
  unsigned short* owb = (unsigned short*)(ws + 9732352);    // 1.11 MB -> ends 10846464
  unsigned short* qpw_hi = (unsigned short*)(ws + 10846464);// 34.8 KB
  unsigned short* qpw_lo = (unsigned short*)(ws + 10881280);// 34.8 KB
  float*    qpb_pad = (float*)(ws + 10916096);              // 2.2 KB
  float*    Wp     = (float*)(ws + 16777216);               // 8.39 MB -> ends ~25.2 MB

  k_fold_part<<<dim3(NCHUNK, 16), dim3(256), 0, stream>>>(pre_w, q_filt, k_filt, Wp);
  k_foldred_bias<<<dim3(257), dim3(256), 0, stream>>>(Wp, pre_b, q_filt, k_filt, Wt_hi, Wt_lo, bias64);
  k_q0v_cs<<<dim3(MROWS / 64), dim3(512), 0, stream>>>(x, Wt_hi, Wt_lo, bias64, decay, Q0V, S);
  k_prep_scan<<<dim3(NB_PREP + BATCH), dim3(576), 0, stream>>>(o_w, qp_w, qp_b, owb, qpw_hi, qpw_lo, qpb_pad, S);
  k_out_fused<<<dim3(MROWS / 64), dim3(1024), 0, stream>>>(Q0V, S, qpw_hi, qpw_lo, qpb_pad, decay, owb, o_b, out);
}